// Round 14
// baseline (740.471 us; speedup 1.0000x reference)
//
#include <hip/hip_runtime.h>
#include <hip/hip_bf16.h>
#include <hip/hip_fp16.h>
#include <math.h>

#define NIT 9   // chebyshev iteration count

typedef _Float16 f16x8 __attribute__((ext_vector_type(8)));
typedef float    f32x4 __attribute__((ext_vector_type(4)));

// wt[c][k] fp16 (c: 0..127 attn, 128..383 out); bias[c] f32
__global__ void conv_w_kernel(const float* __restrict__ w_attn, const float* __restrict__ b_attn,
                              const float* __restrict__ w_out,  const float* __restrict__ b_out,
                              __half* __restrict__ wt, float* __restrict__ bias)
{
    int tid = blockIdx.x * blockDim.x + threadIdx.x;
    if (tid >= 384 * 128) return;
    int c = tid >> 7, k = tid & 127;
    float v = (c < 128) ? w_attn[(size_t)k * 128 + c] : w_out[(size_t)k * 256 + (c - 128)];
    wt[tid] = __float2half(v);
    if (k == 0) bias[c] = (c < 128) ? b_attn[c] : b_out[c - 128];
}

__device__ __forceinline__ f16x8 cvt8(const float* __restrict__ p)
{
    float4 v0 = *(const float4*)p;
    float4 v1 = *(const float4*)(p + 4);
    f16x8 r;
    r[0] = (_Float16)v0.x; r[1] = (_Float16)v0.y;
    r[2] = (_Float16)v0.z; r[3] = (_Float16)v0.w;
    r[4] = (_Float16)v1.x; r[5] = (_Float16)v1.y;
    r[6] = (_Float16)v1.z; r[7] = (_Float16)v1.w;
    return r;
}

// ---------------- MFMA GEMM: [n,128] x [128,384] + bias (f32 feat in) --------
__global__ __launch_bounds__(256) void mfma_gemm_kernel(
    const float* __restrict__ feat, const __half* __restrict__ wt,
    const float* __restrict__ bias,
    __half* __restrict__ a_half, __half* __restrict__ bh, int n)
{
    int w = threadIdx.x >> 6;
    int lane = threadIdx.x & 63;
    int m0 = blockIdx.x * 32;
    int colbase = w * 96;
    int mrow = lane & 15, kgrp = lane >> 4;
    int r0c = m0 + mrow;      if (r0c > n - 1) r0c = n - 1;
    int r1c = m0 + 16 + mrow; if (r1c > n - 1) r1c = n - 1;
    f32x4 acc[2][6] = {};
    #pragma unroll
    for (int ks = 0; ks < 4; ++ks) {
        int k0 = ks * 32 + kgrp * 8;
        f16x8 a0 = cvt8(feat + (size_t)r0c * 128 + k0);
        f16x8 a1 = cvt8(feat + (size_t)r1c * 128 + k0);
        #pragma unroll
        for (int ct = 0; ct < 6; ++ct) {
            int gcol = colbase + ct * 16 + mrow;
            f16x8 b = *(const f16x8*)(wt + (size_t)gcol * 128 + k0);
            acc[0][ct] = __builtin_amdgcn_mfma_f32_16x16x32_f16(a0, b, acc[0][ct], 0, 0, 0);
            acc[1][ct] = __builtin_amdgcn_mfma_f32_16x16x32_f16(a1, b, acc[1][ct], 0, 0, 0);
        }
    }
    #pragma unroll
    for (int rt = 0; rt < 2; ++rt) {
        #pragma unroll
        for (int ct = 0; ct < 6; ++ct) {
            int gcol = colbase + ct * 16 + mrow;
            float bv = bias[gcol];
            #pragma unroll
            for (int j = 0; j < 4; ++j) {
                int grow = m0 + rt * 16 + kgrp * 4 + j;
                if (grow >= n) continue;
                float v = acc[rt][ct][j] + bv;
                if (gcol < 128) a_half[(size_t)grow * 128 + gcol] = __float2half(v);
                else            bh[(size_t)grow * 256 + (gcol - 128)] = __float2half(v);
            }
        }
    }
}

// -------- per-edge attention + row-count (symmetric); 2 units / 16-lane group --
__global__ void edge_attn_sym_kernel(const int* __restrict__ row, const int* __restrict__ col,
                                     const __half* __restrict__ a_half, float* __restrict__ attn,
                                     int* __restrict__ cnt, int E0, int nu)
{
    int gtid = blockIdx.x * blockDim.x + threadIdx.x;
    int g = gtid >> 4;
    int lane = gtid & 15;
    int u0 = 2 * g;
    if (u0 >= nu) return;
    int u1 = u0 + 1;
    bool has1 = (u1 < nu);
    int e0 = (u0 < E0) ? u0 : u0 + E0;
    int e1 = has1 ? ((u1 < E0) ? u1 : u1 + E0) : e0;
    int r0 = row[e0], c0 = col[e0];
    int r1 = row[e1], c1 = col[e1];
    float4 av0 = ((const float4*)(a_half + (size_t)r0 * 128))[lane];
    float4 bv0 = ((const float4*)(a_half + (size_t)c0 * 128))[lane];
    float4 av1 = ((const float4*)(a_half + (size_t)r1 * 128))[lane];
    float4 bv1 = ((const float4*)(a_half + (size_t)c1 * 128))[lane];
    float p0 = 0.f, p1 = 0.f;
    {
        const __half2* a2 = (const __half2*)&av0;
        const __half2* b2 = (const __half2*)&bv0;
        #pragma unroll
        for (int q = 0; q < 4; ++q) {
            float2 fa = __half22float2(a2[q]);
            float2 fb = __half22float2(b2[q]);
            p0 += fa.x * fb.x + fa.y * fb.y;
        }
    }
    {
        const __half2* a2 = (const __half2*)&av1;
        const __half2* b2 = (const __half2*)&bv1;
        #pragma unroll
        for (int q = 0; q < 4; ++q) {
            float2 fa = __half22float2(a2[q]);
            float2 fb = __half22float2(b2[q]);
            p1 += fa.x * fb.x + fa.y * fb.y;
        }
    }
    p0 += __shfl_xor(p0, 1); p0 += __shfl_xor(p0, 2);
    p1 += __shfl_xor(p1, 1); p1 += __shfl_xor(p1, 2);
    int h = lane >> 2, j = lane & 3;
    if (j == 0) {
        float sg0 = 1.0f / (1.0f + __expf(-p0));
        attn[(size_t)e0*4 + h] = sg0;
        if (u0 < E0) attn[(size_t)(e0 + E0)*4 + h] = sg0;
        if (has1) {
            float sg1 = 1.0f / (1.0f + __expf(-p1));
            attn[(size_t)e1*4 + h] = sg1;
            if (u1 < E0) attn[(size_t)(e1 + E0)*4 + h] = sg1;
        }
    }
    if (lane == 0) {
        if (u0 < E0) { atomicAdd(&cnt[r0], 1); atomicAdd(&cnt[c0], 1); }
        if (has1 && u1 < E0) { atomicAdd(&cnt[r1], 1); atomicAdd(&cnt[c1], 1); }
    }
}

// ---------------- CSR build: 3-phase multi-block scan ----------------
__global__ __launch_bounds__(1024) void scanA_kernel(const int* __restrict__ cnt,
                                                     int* __restrict__ local,
                                                     int* __restrict__ bsum, int n)
{
    __shared__ int s[1024];
    int t = threadIdx.x;
    int i = blockIdx.x * 1024 + t;
    int v = (i < n) ? cnt[i] : 0;
    s[t] = v;
    __syncthreads();
    for (int off = 1; off < 1024; off <<= 1) {
        int tmp = (t >= off) ? s[t - off] : 0;
        __syncthreads();
        s[t] += tmp;
        __syncthreads();
    }
    if (i < n) local[i] = s[t] - v;
    if (t == 1023) bsum[blockIdx.x] = s[t];
}

__global__ __launch_bounds__(1024) void scanB_kernel(int* __restrict__ bsum,
                                                     int* __restrict__ rowp,
                                                     int nb, int n)
{
    __shared__ int s[1024];
    int t = threadIdx.x;
    int v = (t < nb) ? bsum[t] : 0;
    s[t] = v;
    __syncthreads();
    for (int off = 1; off < 1024; off <<= 1) {
        int tmp = (t >= off) ? s[t - off] : 0;
        __syncthreads();
        s[t] += tmp;
        __syncthreads();
    }
    if (t < nb) bsum[t] = s[t] - v;
    if (t == nb - 1) rowp[n] = s[t];
}

__global__ void scanC_kernel(int* __restrict__ local_nxt, const int* __restrict__ bsum,
                             int* __restrict__ rowp, int n)
{
    int i = blockIdx.x * blockDim.x + threadIdx.x;
    if (i >= n) return;
    int v = local_nxt[i] + bsum[i >> 10];
    rowp[i] = v;
    local_nxt[i] = v;
}

__global__ void scatter_kernel(const int* __restrict__ row, const int* __restrict__ col,
                               int* __restrict__ next, int* __restrict__ col_s,
                               int* __restrict__ perm, int ne2)
{
    int e = blockIdx.x * blockDim.x + threadIdx.x;
    if (e >= ne2) return;
    int pos = atomicAdd(&next[row[e]], 1);
    col_s[pos] = col[e];
    perm[pos] = e;
}

// -------- deg via CSR (no atomics), fused isq + dw: wave per row --------
__global__ __launch_bounds__(256) void deg_csr_kernel(
    const int* __restrict__ perm, const float* __restrict__ attn,
    const int* __restrict__ rowp, const float* __restrict__ coeff,
    float* __restrict__ isq, float* __restrict__ dw, int E0, int n)
{
    int wid = threadIdx.x >> 6;
    int lane = threadIdx.x & 63;
    int i = blockIdx.x * 4 + wid;
    if (i >= n) return;
    int start = rowp[i], end = rowp[i + 1];
    int h = lane & 3;
    float s = 0.f;
    for (int p = start + (lane >> 2); p < end; p += 16) {
        int e = perm[p];
        s += attn[(size_t)e * 4 + h];
    }
    s += __shfl_xor(s, 4);
    s += __shfl_xor(s, 8);
    s += __shfl_xor(s, 16);
    s += __shfl_xor(s, 32);
    if (lane < 4) {
        float al = attn[(size_t)(2 * E0 + i) * 4 + h];   // self-loop
        s += al;
        float q = (s > 0.f) ? rsqrtf(s) : 0.f;
        isq[(size_t)i * 4 + h] = q;
        dw[(size_t)i * 4 + h] = coeff[h] * al * q * q;
    }
}

// coeff layout: [0..3]=s_h ; [4 + k*4 + h]=c1 ; [4 + NIT*4 + k*4 + h]=c2
__global__ void coeff_kernel(const float* __restrict__ eps_inv, float* __restrict__ coeff)
{
    int h = threadIdx.x;
    if (h >= 4) return;
    float eps = 1.0f / (1.0f + expf(-eps_inv[h]));
    float s = 1.0f - eps;          // delta (theta = 1)
    coeff[h] = s;
    float sigma2 = 2.0f / s;       // 2*sigma1
    float rho = s;                 // rho0 = delta/theta
    for (int k = 0; k < NIT; ++k) {
        float rhon = 1.0f / (sigma2 - rho);
        coeff[4 + k*4 + h] = rhon * rho;
        coeff[4 + NIT*4 + k*4 + h] = 2.0f * rhon / s;
        rho = rhon;
    }
}

__global__ void vals_kernel(const int* __restrict__ perm, const int* __restrict__ row,
                            const int* __restrict__ col, const float* __restrict__ attn,
                            const float* __restrict__ isq, const float* __restrict__ coeff,
                            __half* __restrict__ valsh, int ne2)
{
    int p = blockIdx.x * blockDim.x + threadIdx.x;
    if (p >= ne2) return;
    int e = perm[p];
    int r0 = row[e], c0 = col[e];
    #pragma unroll
    for (int h = 0; h < 4; ++h)
        valsh[(size_t)p*4 + h] = __float2half(
            coeff[h] * attn[(size_t)e*4 + h]
            * isq[(size_t)r0*4 + h] * isq[(size_t)c0*4 + h]);
}

// ------------- gather: 16-batch main loop + exec-masked 16-batch tail -------------
// One latency round for typical (deg<=16) rows. Accumulation order unchanged
// (p-ascending) -> bit-identical to the 8-batch version.
__device__ __forceinline__ void gather_row(
    const __half2* __restrict__ x2, const __half* __restrict__ valsh,
    const int* __restrict__ col_s, int start, int end, int lane, int h,
    float& a0, float& a1, float& a2, float& a3)
{
    int p = start;
    for (; p + 16 <= end; p += 16) {
        float w[16];
        uint2 u[16];
        #pragma unroll
        for (int q = 0; q < 16; ++q) {
            int c = col_s[p + q];
            w[q] = __half2float(valsh[(size_t)(p + q) * 4 + h]);
            u[q] = *(const uint2*)(x2 + (size_t)c * 128 + lane * 2);
        }
        #pragma unroll
        for (int q = 0; q < 16; ++q) {
            float2 f0 = __half22float2(*(__half2*)&u[q].x);
            float2 f1 = __half22float2(*(__half2*)&u[q].y);
            a0 += w[q] * f0.x; a1 += w[q] * f0.y;
            a2 += w[q] * f1.x; a3 += w[q] * f1.y;
        }
    }
    int len = end - p;   // 0..15
    {
        float w[16];
        uint2 u[16];
        #pragma unroll
        for (int q = 0; q < 16; ++q) {
            if (q < len) {
                int c = col_s[p + q];
                w[q] = __half2float(valsh[(size_t)(p + q) * 4 + h]);
                u[q] = *(const uint2*)(x2 + (size_t)c * 128 + lane * 2);
            }
        }
        #pragma unroll
        for (int q = 0; q < 16; ++q) {
            if (q < len) {
                float2 f0 = __half22float2(*(__half2*)&u[q].x);
                float2 f1 = __half22float2(*(__half2*)&u[q].y);
                a0 += w[q] * f0.x; a1 += w[q] * f0.y;
                a2 += w[q] * f1.x; a3 += w[q] * f1.y;
            }
        }
    }
}

// ---------------- fused chebyshev iteration (ONE wave per block) ----------------
template <bool FINAL>
__global__ __launch_bounds__(64) void cheb_kernel(
    const __half* __restrict__ xch, const __half* __restrict__ xph,
    const __half* __restrict__ bh, const float* __restrict__ dw,
    __half* __restrict__ xnh, float* __restrict__ out,
    const __half* __restrict__ valsh, const int* __restrict__ col_s,
    const int* __restrict__ row_ptr, const float* __restrict__ coeff, int k, int n)
{
    int lane = threadIdx.x;
    int i = blockIdx.x;
    if (i >= n) return;
    int h = lane >> 4;
    const __half2* x2 = (const __half2*)xch;
    int start = row_ptr[i], end = row_ptr[i + 1];
    float a0 = 0.f, a1 = 0.f, a2 = 0.f, a3 = 0.f;
    gather_row(x2, valsh, col_s, start, end, lane, h, a0, a1, a2, a3);
    size_t idx2 = (size_t)i * 128 + lane * 2;
    float2 xc0 = __half22float2(x2[idx2]);
    float2 xc1 = __half22float2(x2[idx2 + 1]);
    float2 xp0 = xph ? __half22float2(((const __half2*)xph)[idx2])     : make_float2(0.f, 0.f);
    float2 xp1 = xph ? __half22float2(((const __half2*)xph)[idx2 + 1]) : make_float2(0.f, 0.f);
    float2 bv0 = __half22float2(((const __half2*)bh)[idx2]);
    float2 bv1 = __half22float2(((const __half2*)bh)[idx2 + 1]);
    float dwv = dw[(size_t)i * 4 + h];
    float r0 = bv0.x - xc0.x + a0 + dwv * xc0.x;
    float r1 = bv0.y - xc0.y + a1 + dwv * xc0.y;
    float r2 = bv1.x - xc1.x + a2 + dwv * xc1.x;
    float r3 = bv1.y - xc1.y + a3 + dwv * xc1.y;
    float c1v = coeff[4 + k*4 + h];
    float c2v = coeff[4 + NIT*4 + k*4 + h];
    float v0 = xc0.x + c1v * (xc0.x - xp0.x) + c2v * r0;
    float v1 = xc0.y + c1v * (xc0.y - xp0.y) + c2v * r1;
    float v2 = xc1.x + c1v * (xc1.x - xp1.x) + c2v * r2;
    float v3 = xc1.y + c1v * (xc1.y - xp1.y) + c2v * r3;
    if (FINAL) {
        v0 += __shfl_xor(v0, 16); v0 += __shfl_xor(v0, 32);
        v1 += __shfl_xor(v1, 16); v1 += __shfl_xor(v1, 32);
        v2 += __shfl_xor(v2, 16); v2 += __shfl_xor(v2, 32);
        v3 += __shfl_xor(v3, 16); v3 += __shfl_xor(v3, 32);
        if (lane < 16) {
            float4 o = make_float4(0.25f*v0, 0.25f*v1, 0.25f*v2, 0.25f*v3);
            ((float4*)out)[(size_t)i * 16 + lane] = o;
        }
    } else {
        __half2* xo = (__half2*)xnh;
        xo[idx2]     = __floats2half2_rn(v0, v1);
        xo[idx2 + 1] = __floats2half2_rn(v2, v3);
    }
}

__global__ void fill_kernel(float* __restrict__ out, int sz, float v)
{
    int i = blockIdx.x * blockDim.x + threadIdx.x;
    if (i < sz) out[i] = v;
}

extern "C" void kernel_launch(void* const* d_in, const int* in_sizes, int n_in,
                              void* d_out, int out_size, void* d_ws, size_t ws_size,
                              hipStream_t stream)
{
    const int*   row     = (const int*)d_in[0];
    const int*   col     = (const int*)d_in[1];
    const float* feat    = (const float*)d_in[2];
    const float* w_attn  = (const float*)d_in[3];
    const float* b_attn  = (const float*)d_in[4];
    const float* w_out   = (const float*)d_in[5];
    const float* b_out   = (const float*)d_in[6];
    const float* eps_inv = (const float*)d_in[7];
    float* out = (float*)d_out;

    int n  = in_sizes[2] / 128;
    int ne = in_sizes[0];
    int E0 = (ne - n) / 2;          // setup: edges = [r,c],[c,r],loops
    int ne2 = 2 * E0;               // CSR edges (loops excluded)
    int nb = (n + 1023) / 1024;     // scan blocks

    // workspace layout
    char* wsb = (char*)d_ws;
    size_t off = 0;
    auto alloc = [&](size_t bytes) -> void* {
        void* p = wsb + off;
        off += (bytes + 255) & ~(size_t)255;
        return p;
    };
    __half* a_half = (__half*)alloc((size_t)n * 128 * 2);
    __half* bh     = (__half*)alloc((size_t)n * 256 * 2);
    __half* hA     = (__half*)alloc((size_t)n * 256 * 2);
    __half* hB     = (__half*)alloc((size_t)n * 256 * 2);
    __half* wt     = (__half*)alloc((size_t)384 * 128 * 2);
    float*  bias   = (float*)alloc((size_t)384 * 4);
    __half* valsh  = (__half*)alloc((size_t)ne2 * 4 * 2);
    float*  isq    = (float*)alloc((size_t)n * 4 * 4);
    float*  dw     = (float*)alloc((size_t)n * 4 * 4);
    int*    rowp   = (int*)alloc((size_t)(n + 1) * 4);
    int*    col_s  = (int*)alloc((size_t)ne2 * 4);
    int*    bsum   = (int*)alloc((size_t)((nb + 63) & ~63) * 4);
    float*  coeff  = (float*)alloc((size_t)(4 + 8 * NIT) * 4);

    // overlays: consumed before the solve loop writes hA/hB
    int*   perm = (int*)hA;                                   // ne2*4 <= n*512
    int*   cnt  = (int*)((char*)hA + (((size_t)ne2*4 + 255) & ~(size_t)255));
    int*   nxt  = cnt + ((n + 64) & ~63);
    float* attn = (float*)hB;                                 // ne*4*4 <= n*512

    if (off > ws_size) {  // sentinel: distinctive absmax tells us ws is too small
        fill_kernel<<<(out_size + 255) / 256, 256, 0, stream>>>(out, out_size, 1e9f);
        return;
    }

    hipMemsetAsync(cnt, 0, (size_t)n * 4, stream);

    conv_w_kernel<<<(384 * 128 + 255) / 256, 256, 0, stream>>>(w_attn, b_attn,
                                                               w_out, b_out, wt, bias);
    mfma_gemm_kernel<<<(n + 31) / 32, 256, 0, stream>>>(feat, wt, bias, a_half, bh, n);
    coeff_kernel<<<1, 64, 0, stream>>>(eps_inv, coeff);

    int nu = E0 + n;  // edge-units: one per symmetric pair + one per loop
    int ngroups = (nu + 1) / 2;
    int ublocks = (ngroups * 16 + 255) / 256;
    edge_attn_sym_kernel<<<ublocks, 256, 0, stream>>>(row, col, a_half, attn,
                                                      cnt, E0, nu);

    scanA_kernel<<<nb, 1024, 0, stream>>>(cnt, nxt, bsum, n);
    scanB_kernel<<<1, 1024, 0, stream>>>(bsum, rowp, nb, n);
    scanC_kernel<<<(n + 255) / 256, 256, 0, stream>>>(nxt, bsum, rowp, n);
    scatter_kernel<<<(ne2 + 255) / 256, 256, 0, stream>>>(row, col, nxt, col_s, perm, ne2);
    deg_csr_kernel<<<(n + 3) / 4, 256, 0, stream>>>(perm, attn, rowp, coeff,
                                                    isq, dw, E0, n);
    vals_kernel<<<(ne2 + 255) / 256, 256, 0, stream>>>(perm, row, col, attn, isq,
                                                       coeff, valsh, ne2);

    // x0 = bh, x1 -> hA, x2 -> hB, then ping-pong (x_{k+1} overwrites x_{k-1})
    cheb_kernel<false><<<n, 64, 0, stream>>>(
        bh, nullptr, bh, dw, hA, nullptr, valsh, col_s, rowp, coeff, 0, n);
    cheb_kernel<false><<<n, 64, 0, stream>>>(
        hA, bh, bh, dw, hB, nullptr, valsh, col_s, rowp, coeff, 1, n);
    for (int k = 2; k < NIT; ++k) {
        __half* cur = (k & 1) ? hA : hB;
        __half* prv = (k & 1) ? hB : hA;
        if (k == NIT - 1)
            cheb_kernel<true><<<n, 64, 0, stream>>>(
                cur, prv, bh, dw, nullptr, out, valsh, col_s, rowp, coeff, k, n);
        else
            cheb_kernel<false><<<n, 64, 0, stream>>>(
                cur, prv, bh, dw, prv, nullptr, valsh, col_s, rowp, coeff, k, n);
    }
}

// Round 15
// 667.149 us; speedup vs baseline: 1.1099x; 1.1099x over previous
//
#include <hip/hip_runtime.h>
#include <hip/hip_bf16.h>
#include <hip/hip_fp16.h>
#include <math.h>

#define NIT 9   // chebyshev iteration count

typedef _Float16 f16x8 __attribute__((ext_vector_type(8)));
typedef float    f32x4 __attribute__((ext_vector_type(4)));

// wt[c][k] fp16 (c: 0..127 attn, 128..383 out); bias[c] f32
__global__ void conv_w_kernel(const float* __restrict__ w_attn, const float* __restrict__ b_attn,
                              const float* __restrict__ w_out,  const float* __restrict__ b_out,
                              __half* __restrict__ wt, float* __restrict__ bias)
{
    int tid = blockIdx.x * blockDim.x + threadIdx.x;
    if (tid >= 384 * 128) return;
    int c = tid >> 7, k = tid & 127;
    float v = (c < 128) ? w_attn[(size_t)k * 128 + c] : w_out[(size_t)k * 256 + (c - 128)];
    wt[tid] = __float2half(v);
    if (k == 0) bias[c] = (c < 128) ? b_attn[c] : b_out[c - 128];
}

__device__ __forceinline__ f16x8 cvt8(const float* __restrict__ p)
{
    float4 v0 = *(const float4*)p;
    float4 v1 = *(const float4*)(p + 4);
    f16x8 r;
    r[0] = (_Float16)v0.x; r[1] = (_Float16)v0.y;
    r[2] = (_Float16)v0.z; r[3] = (_Float16)v0.w;
    r[4] = (_Float16)v1.x; r[5] = (_Float16)v1.y;
    r[6] = (_Float16)v1.z; r[7] = (_Float16)v1.w;
    return r;
}

// ---------------- MFMA GEMM: [n,128] x [128,384] + bias (f32 feat in) --------
__global__ __launch_bounds__(256) void mfma_gemm_kernel(
    const float* __restrict__ feat, const __half* __restrict__ wt,
    const float* __restrict__ bias,
    __half* __restrict__ a_half, __half* __restrict__ bh, int n)
{
    int w = threadIdx.x >> 6;
    int lane = threadIdx.x & 63;
    int m0 = blockIdx.x * 32;
    int colbase = w * 96;
    int mrow = lane & 15, kgrp = lane >> 4;
    int r0c = m0 + mrow;      if (r0c > n - 1) r0c = n - 1;
    int r1c = m0 + 16 + mrow; if (r1c > n - 1) r1c = n - 1;
    f32x4 acc[2][6] = {};
    #pragma unroll
    for (int ks = 0; ks < 4; ++ks) {
        int k0 = ks * 32 + kgrp * 8;
        f16x8 a0 = cvt8(feat + (size_t)r0c * 128 + k0);
        f16x8 a1 = cvt8(feat + (size_t)r1c * 128 + k0);
        #pragma unroll
        for (int ct = 0; ct < 6; ++ct) {
            int gcol = colbase + ct * 16 + mrow;
            f16x8 b = *(const f16x8*)(wt + (size_t)gcol * 128 + k0);
            acc[0][ct] = __builtin_amdgcn_mfma_f32_16x16x32_f16(a0, b, acc[0][ct], 0, 0, 0);
            acc[1][ct] = __builtin_amdgcn_mfma_f32_16x16x32_f16(a1, b, acc[1][ct], 0, 0, 0);
        }
    }
    #pragma unroll
    for (int rt = 0; rt < 2; ++rt) {
        #pragma unroll
        for (int ct = 0; ct < 6; ++ct) {
            int gcol = colbase + ct * 16 + mrow;
            float bv = bias[gcol];
            #pragma unroll
            for (int j = 0; j < 4; ++j) {
                int grow = m0 + rt * 16 + kgrp * 4 + j;
                if (grow >= n) continue;
                float v = acc[rt][ct][j] + bv;
                if (gcol < 128) a_half[(size_t)grow * 128 + gcol] = __float2half(v);
                else            bh[(size_t)grow * 256 + (gcol - 128)] = __float2half(v);
            }
        }
    }
}

// -------- per-edge attention + row-count (symmetric); 4 units / 16-lane group --
__global__ void edge_attn_sym_kernel(const int* __restrict__ row, const int* __restrict__ col,
                                     const __half* __restrict__ a_half, float* __restrict__ attn,
                                     int* __restrict__ cnt, int E0, int nu)
{
    int gtid = blockIdx.x * blockDim.x + threadIdx.x;
    int g = gtid >> 4;
    int lane = gtid & 15;
    int ubase = 4 * g;
    if (ubase >= nu) return;
    int r[4], c[4], e[4];
    float4 av[4], bv[4];
    #pragma unroll
    for (int t = 0; t < 4; ++t) {
        int u = ubase + t;
        int uc = (u < nu) ? u : ubase;
        e[t] = (uc < E0) ? uc : uc + E0;
        r[t] = row[e[t]];
        c[t] = col[e[t]];
        av[t] = ((const float4*)(a_half + (size_t)r[t] * 128))[lane];
        bv[t] = ((const float4*)(a_half + (size_t)c[t] * 128))[lane];
    }
    float p[4];
    #pragma unroll
    for (int t = 0; t < 4; ++t) {
        const __half2* a2 = (const __half2*)&av[t];
        const __half2* b2 = (const __half2*)&bv[t];
        float s = 0.f;
        #pragma unroll
        for (int q = 0; q < 4; ++q) {
            float2 fa = __half22float2(a2[q]);
            float2 fb = __half22float2(b2[q]);
            s += fa.x * fb.x + fa.y * fb.y;
        }
        s += __shfl_xor(s, 1);
        s += __shfl_xor(s, 2);
        p[t] = s;
    }
    int h = lane >> 2, j = lane & 3;
    if (j == 0) {
        #pragma unroll
        for (int t = 0; t < 4; ++t) {
            int u = ubase + t;
            if (u >= nu) break;
            float sg = 1.0f / (1.0f + __expf(-p[t]));
            attn[(size_t)e[t]*4 + h] = sg;
            if (u < E0) attn[(size_t)(e[t] + E0)*4 + h] = sg;
        }
    }
    if (lane == 0) {
        #pragma unroll
        for (int t = 0; t < 4; ++t) {
            int u = ubase + t;
            if (u < nu && u < E0) { atomicAdd(&cnt[r[t]], 1); atomicAdd(&cnt[c[t]], 1); }
        }
    }
}

// ---------------- CSR build: 3-phase multi-block scan ----------------
__global__ __launch_bounds__(1024) void scanA_kernel(const int* __restrict__ cnt,
                                                     int* __restrict__ local,
                                                     int* __restrict__ bsum, int n)
{
    __shared__ int s[1024];
    int t = threadIdx.x;
    int i = blockIdx.x * 1024 + t;
    int v = (i < n) ? cnt[i] : 0;
    s[t] = v;
    __syncthreads();
    for (int off = 1; off < 1024; off <<= 1) {
        int tmp = (t >= off) ? s[t - off] : 0;
        __syncthreads();
        s[t] += tmp;
        __syncthreads();
    }
    if (i < n) local[i] = s[t] - v;
    if (t == 1023) bsum[blockIdx.x] = s[t];
}

__global__ __launch_bounds__(1024) void scanB_kernel(int* __restrict__ bsum,
                                                     int* __restrict__ rowp,
                                                     int nb, int n)
{
    __shared__ int s[1024];
    int t = threadIdx.x;
    int v = (t < nb) ? bsum[t] : 0;
    s[t] = v;
    __syncthreads();
    for (int off = 1; off < 1024; off <<= 1) {
        int tmp = (t >= off) ? s[t - off] : 0;
        __syncthreads();
        s[t] += tmp;
        __syncthreads();
    }
    if (t < nb) bsum[t] = s[t] - v;
    if (t == nb - 1) rowp[n] = s[t];
}

__global__ void scanC_kernel(int* __restrict__ local_nxt, const int* __restrict__ bsum,
                             int* __restrict__ rowp, int n)
{
    int i = blockIdx.x * blockDim.x + threadIdx.x;
    if (i >= n) return;
    int v = local_nxt[i] + bsum[i >> 10];
    rowp[i] = v;
    local_nxt[i] = v;
}

__global__ void scatter_kernel(const int* __restrict__ row, const int* __restrict__ col,
                               int* __restrict__ next, int* __restrict__ col_s,
                               int* __restrict__ perm, int ne2)
{
    int e = blockIdx.x * blockDim.x + threadIdx.x;
    if (e >= ne2) return;
    int pos = atomicAdd(&next[row[e]], 1);
    col_s[pos] = col[e];
    perm[pos] = e;
}

// -------- deg via CSR (no atomics), fused isq + dw: wave per row --------
__global__ __launch_bounds__(256) void deg_csr_kernel(
    const int* __restrict__ perm, const float* __restrict__ attn,
    const int* __restrict__ rowp, const float* __restrict__ coeff,
    float* __restrict__ isq, float* __restrict__ dw, int E0, int n)
{
    int wid = threadIdx.x >> 6;
    int lane = threadIdx.x & 63;
    int i = blockIdx.x * 4 + wid;
    if (i >= n) return;
    int start = rowp[i], end = rowp[i + 1];
    int h = lane & 3;
    float s = 0.f;
    for (int p = start + (lane >> 2); p < end; p += 16) {
        int e = perm[p];
        s += attn[(size_t)e * 4 + h];
    }
    s += __shfl_xor(s, 4);
    s += __shfl_xor(s, 8);
    s += __shfl_xor(s, 16);
    s += __shfl_xor(s, 32);
    if (lane < 4) {
        float al = attn[(size_t)(2 * E0 + i) * 4 + h];   // self-loop
        s += al;
        float q = (s > 0.f) ? rsqrtf(s) : 0.f;
        isq[(size_t)i * 4 + h] = q;
        dw[(size_t)i * 4 + h] = coeff[h] * al * q * q;
    }
}

// coeff layout: [0..3]=s_h ; [4 + k*4 + h]=c1 ; [4 + NIT*4 + k*4 + h]=c2
__global__ void coeff_kernel(const float* __restrict__ eps_inv, float* __restrict__ coeff)
{
    int h = threadIdx.x;
    if (h >= 4) return;
    float eps = 1.0f / (1.0f + expf(-eps_inv[h]));
    float s = 1.0f - eps;          // delta (theta = 1)
    coeff[h] = s;
    float sigma2 = 2.0f / s;       // 2*sigma1
    float rho = s;                 // rho0 = delta/theta
    for (int k = 0; k < NIT; ++k) {
        float rhon = 1.0f / (sigma2 - rho);
        coeff[4 + k*4 + h] = rhon * rho;
        coeff[4 + NIT*4 + k*4 + h] = 2.0f * rhon / s;
        rho = rhon;
    }
}

__global__ void vals_kernel(const int* __restrict__ perm, const int* __restrict__ row,
                            const int* __restrict__ col, const float* __restrict__ attn,
                            const float* __restrict__ isq, const float* __restrict__ coeff,
                            __half* __restrict__ valsh, int ne2)
{
    int p = blockIdx.x * blockDim.x + threadIdx.x;
    if (p >= ne2) return;
    int e = perm[p];
    int r0 = row[e], c0 = col[e];
    #pragma unroll
    for (int h = 0; h < 4; ++h)
        valsh[(size_t)p*4 + h] = __float2half(
            coeff[h] * attn[(size_t)e*4 + h]
            * isq[(size_t)r0*4 + h] * isq[(size_t)c0*4 + h]);
}

// ------------- gather: 8-batch main loop + exec-masked 8-batch tail -------------
// (round-13 version — verified 55.3 us/iter at 74% occupancy)
__device__ __forceinline__ void gather_row(
    const __half2* __restrict__ x2, const __half* __restrict__ valsh,
    const int* __restrict__ col_s, int start, int end, int lane, int h,
    float& a0, float& a1, float& a2, float& a3)
{
    int p = start;
    for (; p + 8 <= end; p += 8) {
        float w[8];
        uint2 u[8];
        #pragma unroll
        for (int q = 0; q < 8; ++q) {
            int c = col_s[p + q];
            w[q] = __half2float(valsh[(size_t)(p + q) * 4 + h]);
            u[q] = *(const uint2*)(x2 + (size_t)c * 128 + lane * 2);
        }
        #pragma unroll
        for (int q = 0; q < 8; ++q) {
            float2 f0 = __half22float2(*(__half2*)&u[q].x);
            float2 f1 = __half22float2(*(__half2*)&u[q].y);
            a0 += w[q] * f0.x; a1 += w[q] * f0.y;
            a2 += w[q] * f1.x; a3 += w[q] * f1.y;
        }
    }
    int len = end - p;   // 0..7
    {
        float w[8];
        uint2 u[8];
        #pragma unroll
        for (int q = 0; q < 8; ++q) {
            if (q < len) {
                int c = col_s[p + q];
                w[q] = __half2float(valsh[(size_t)(p + q) * 4 + h]);
                u[q] = *(const uint2*)(x2 + (size_t)c * 128 + lane * 2);
            }
        }
        #pragma unroll
        for (int q = 0; q < 8; ++q) {
            if (q < len) {
                float2 f0 = __half22float2(*(__half2*)&u[q].x);
                float2 f1 = __half22float2(*(__half2*)&u[q].y);
                a0 += w[q] * f0.x; a1 += w[q] * f0.y;
                a2 += w[q] * f1.x; a3 += w[q] * f1.y;
            }
        }
    }
}

// ---------------- fused chebyshev iteration (ONE wave per block) ----------------
// Stream loads (xc/xp/b/dw) hoisted ABOVE the gather so their latency overlaps it.
template <bool FINAL>
__global__ __launch_bounds__(64) void cheb_kernel(
    const __half* __restrict__ xch, const __half* __restrict__ xph,
    const __half* __restrict__ bh, const float* __restrict__ dw,
    __half* __restrict__ xnh, float* __restrict__ out,
    const __half* __restrict__ valsh, const int* __restrict__ col_s,
    const int* __restrict__ row_ptr, const float* __restrict__ coeff, int k, int n)
{
    int lane = threadIdx.x;
    int i = blockIdx.x;
    if (i >= n) return;
    int h = lane >> 4;
    const __half2* x2 = (const __half2*)xch;
    size_t idx2 = (size_t)i * 128 + lane * 2;
    // issue independent stream loads first — latency hides under the gather
    float2 xc0 = __half22float2(x2[idx2]);
    float2 xc1 = __half22float2(x2[idx2 + 1]);
    float2 xp0 = xph ? __half22float2(((const __half2*)xph)[idx2])     : make_float2(0.f, 0.f);
    float2 xp1 = xph ? __half22float2(((const __half2*)xph)[idx2 + 1]) : make_float2(0.f, 0.f);
    float2 bv0 = __half22float2(((const __half2*)bh)[idx2]);
    float2 bv1 = __half22float2(((const __half2*)bh)[idx2 + 1]);
    float dwv = dw[(size_t)i * 4 + h];
    int start = row_ptr[i], end = row_ptr[i + 1];
    float a0 = 0.f, a1 = 0.f, a2 = 0.f, a3 = 0.f;
    gather_row(x2, valsh, col_s, start, end, lane, h, a0, a1, a2, a3);
    float r0 = bv0.x - xc0.x + a0 + dwv * xc0.x;
    float r1 = bv0.y - xc0.y + a1 + dwv * xc0.y;
    float r2 = bv1.x - xc1.x + a2 + dwv * xc1.x;
    float r3 = bv1.y - xc1.y + a3 + dwv * xc1.y;
    float c1v = coeff[4 + k*4 + h];
    float c2v = coeff[4 + NIT*4 + k*4 + h];
    float v0 = xc0.x + c1v * (xc0.x - xp0.x) + c2v * r0;
    float v1 = xc0.y + c1v * (xc0.y - xp0.y) + c2v * r1;
    float v2 = xc1.x + c1v * (xc1.x - xp1.x) + c2v * r2;
    float v3 = xc1.y + c1v * (xc1.y - xp1.y) + c2v * r3;
    if (FINAL) {
        v0 += __shfl_xor(v0, 16); v0 += __shfl_xor(v0, 32);
        v1 += __shfl_xor(v1, 16); v1 += __shfl_xor(v1, 32);
        v2 += __shfl_xor(v2, 16); v2 += __shfl_xor(v2, 32);
        v3 += __shfl_xor(v3, 16); v3 += __shfl_xor(v3, 32);
        if (lane < 16) {
            float4 o = make_float4(0.25f*v0, 0.25f*v1, 0.25f*v2, 0.25f*v3);
            ((float4*)out)[(size_t)i * 16 + lane] = o;
        }
    } else {
        __half2* xo = (__half2*)xnh;
        xo[idx2]     = __floats2half2_rn(v0, v1);
        xo[idx2 + 1] = __floats2half2_rn(v2, v3);
    }
}

__global__ void fill_kernel(float* __restrict__ out, int sz, float v)
{
    int i = blockIdx.x * blockDim.x + threadIdx.x;
    if (i < sz) out[i] = v;
}

extern "C" void kernel_launch(void* const* d_in, const int* in_sizes, int n_in,
                              void* d_out, int out_size, void* d_ws, size_t ws_size,
                              hipStream_t stream)
{
    const int*   row     = (const int*)d_in[0];
    const int*   col     = (const int*)d_in[1];
    const float* feat    = (const float*)d_in[2];
    const float* w_attn  = (const float*)d_in[3];
    const float* b_attn  = (const float*)d_in[4];
    const float* w_out   = (const float*)d_in[5];
    const float* b_out   = (const float*)d_in[6];
    const float* eps_inv = (const float*)d_in[7];
    float* out = (float*)d_out;

    int n  = in_sizes[2] / 128;
    int ne = in_sizes[0];
    int E0 = (ne - n) / 2;          // setup: edges = [r,c],[c,r],loops
    int ne2 = 2 * E0;               // CSR edges (loops excluded)
    int nb = (n + 1023) / 1024;     // scan blocks

    // workspace layout
    char* wsb = (char*)d_ws;
    size_t off = 0;
    auto alloc = [&](size_t bytes) -> void* {
        void* p = wsb + off;
        off += (bytes + 255) & ~(size_t)255;
        return p;
    };
    __half* a_half = (__half*)alloc((size_t)n * 128 * 2);
    __half* bh     = (__half*)alloc((size_t)n * 256 * 2);
    __half* hA     = (__half*)alloc((size_t)n * 256 * 2);
    __half* hB     = (__half*)alloc((size_t)n * 256 * 2);
    __half* wt     = (__half*)alloc((size_t)384 * 128 * 2);
    float*  bias   = (float*)alloc((size_t)384 * 4);
    __half* valsh  = (__half*)alloc((size_t)ne2 * 4 * 2);
    float*  isq    = (float*)alloc((size_t)n * 4 * 4);
    float*  dw     = (float*)alloc((size_t)n * 4 * 4);
    int*    rowp   = (int*)alloc((size_t)(n + 1) * 4);
    int*    col_s  = (int*)alloc((size_t)ne2 * 4);
    int*    bsum   = (int*)alloc((size_t)((nb + 63) & ~63) * 4);
    float*  coeff  = (float*)alloc((size_t)(4 + 8 * NIT) * 4);

    // overlays: consumed before the solve loop writes hA/hB
    int*   perm = (int*)hA;                                   // ne2*4 <= n*512
    int*   cnt  = (int*)((char*)hA + (((size_t)ne2*4 + 255) & ~(size_t)255));
    int*   nxt  = cnt + ((n + 64) & ~63);
    float* attn = (float*)hB;                                 // ne*4*4 <= n*512

    if (off > ws_size) {  // sentinel: distinctive absmax tells us ws is too small
        fill_kernel<<<(out_size + 255) / 256, 256, 0, stream>>>(out, out_size, 1e9f);
        return;
    }

    hipMemsetAsync(cnt, 0, (size_t)n * 4, stream);

    conv_w_kernel<<<(384 * 128 + 255) / 256, 256, 0, stream>>>(w_attn, b_attn,
                                                               w_out, b_out, wt, bias);
    mfma_gemm_kernel<<<(n + 31) / 32, 256, 0, stream>>>(feat, wt, bias, a_half, bh, n);
    coeff_kernel<<<1, 64, 0, stream>>>(eps_inv, coeff);

    int nu = E0 + n;  // edge-units: one per symmetric pair + one per loop
    int ngroups = (nu + 3) / 4;
    int ublocks = (ngroups * 16 + 255) / 256;
    edge_attn_sym_kernel<<<ublocks, 256, 0, stream>>>(row, col, a_half, attn,
                                                      cnt, E0, nu);

    scanA_kernel<<<nb, 1024, 0, stream>>>(cnt, nxt, bsum, n);
    scanB_kernel<<<1, 1024, 0, stream>>>(bsum, rowp, nb, n);
    scanC_kernel<<<(n + 255) / 256, 256, 0, stream>>>(nxt, bsum, rowp, n);
    scatter_kernel<<<(ne2 + 255) / 256, 256, 0, stream>>>(row, col, nxt, col_s, perm, ne2);
    deg_csr_kernel<<<(n + 3) / 4, 256, 0, stream>>>(perm, attn, rowp, coeff,
                                                    isq, dw, E0, n);
    vals_kernel<<<(ne2 + 255) / 256, 256, 0, stream>>>(perm, row, col, attn, isq,
                                                       coeff, valsh, ne2);

    // x0 = bh, x1 -> hA, x2 -> hB, then ping-pong (x_{k+1} overwrites x_{k-1})
    cheb_kernel<false><<<n, 64, 0, stream>>>(
        bh, nullptr, bh, dw, hA, nullptr, valsh, col_s, rowp, coeff, 0, n);
    cheb_kernel<false><<<n, 64, 0, stream>>>(
        hA, bh, bh, dw, hB, nullptr, valsh, col_s, rowp, coeff, 1, n);
    for (int k = 2; k < NIT; ++k) {
        __half* cur = (k & 1) ? hA : hB;
        __half* prv = (k & 1) ? hB : hA;
        if (k == NIT - 1)
            cheb_kernel<true><<<n, 64, 0, stream>>>(
                cur, prv, bh, dw, nullptr, out, valsh, col_s, rowp, coeff, k, n);
        else
            cheb_kernel<false><<<n, 64, 0, stream>>>(
                cur, prv, bh, dw, prv, nullptr, valsh, col_s, rowp, coeff, k, n);
    }
}

// Round 16
// 660.923 us; speedup vs baseline: 1.1204x; 1.0094x over previous
//
#include <hip/hip_runtime.h>
#include <hip/hip_bf16.h>
#include <hip/hip_fp16.h>
#include <math.h>

#define NIT 9   // chebyshev iteration count

typedef _Float16 f16x8 __attribute__((ext_vector_type(8)));
typedef float    f32x4 __attribute__((ext_vector_type(4)));

// wt[c][k] fp16 (c: 0..127 attn, 128..383 out); bias[c] f32
__global__ void conv_w_kernel(const float* __restrict__ w_attn, const float* __restrict__ b_attn,
                              const float* __restrict__ w_out,  const float* __restrict__ b_out,
                              __half* __restrict__ wt, float* __restrict__ bias)
{
    int tid = blockIdx.x * blockDim.x + threadIdx.x;
    if (tid >= 384 * 128) return;
    int c = tid >> 7, k = tid & 127;
    float v = (c < 128) ? w_attn[(size_t)k * 128 + c] : w_out[(size_t)k * 256 + (c - 128)];
    wt[tid] = __float2half(v);
    if (k == 0) bias[c] = (c < 128) ? b_attn[c] : b_out[c - 128];
}

__device__ __forceinline__ f16x8 cvt8(const float* __restrict__ p)
{
    float4 v0 = *(const float4*)p;
    float4 v1 = *(const float4*)(p + 4);
    f16x8 r;
    r[0] = (_Float16)v0.x; r[1] = (_Float16)v0.y;
    r[2] = (_Float16)v0.z; r[3] = (_Float16)v0.w;
    r[4] = (_Float16)v1.x; r[5] = (_Float16)v1.y;
    r[6] = (_Float16)v1.z; r[7] = (_Float16)v1.w;
    return r;
}

// ---------------- MFMA GEMM: [n,128] x [128,384] + bias (f32 feat in) --------
// Operand-swapped: D = wt_tile * feat_tile^T, so each lane holds one node and
// 4 CONSECUTIVE output columns -> packed 8B stores instead of 48 scalar 2B.
__global__ __launch_bounds__(256) void mfma_gemm_kernel(
    const float* __restrict__ feat, const __half* __restrict__ wt,
    const float* __restrict__ bias,
    __half* __restrict__ a_half, __half* __restrict__ bh, int n)
{
    int w = threadIdx.x >> 6;
    int lane = threadIdx.x & 63;
    int m0 = blockIdx.x * 32;
    int colbase = w * 96;
    int mrow = lane & 15, kgrp = lane >> 4;
    int r0c = m0 + mrow;      if (r0c > n - 1) r0c = n - 1;
    int r1c = m0 + 16 + mrow; if (r1c > n - 1) r1c = n - 1;
    f32x4 acc[2][6] = {};
    #pragma unroll
    for (int ks = 0; ks < 4; ++ks) {
        int k0 = ks * 32 + kgrp * 8;
        f16x8 a0 = cvt8(feat + (size_t)r0c * 128 + k0);
        f16x8 a1 = cvt8(feat + (size_t)r1c * 128 + k0);
        #pragma unroll
        for (int ct = 0; ct < 6; ++ct) {
            int gcol = colbase + ct * 16 + mrow;
            f16x8 b = *(const f16x8*)(wt + (size_t)gcol * 128 + k0);
            // A-operand = weights (rows = output cols), B-operand = feat (cols = nodes)
            acc[0][ct] = __builtin_amdgcn_mfma_f32_16x16x32_f16(b, a0, acc[0][ct], 0, 0, 0);
            acc[1][ct] = __builtin_amdgcn_mfma_f32_16x16x32_f16(b, a1, acc[1][ct], 0, 0, 0);
        }
    }
    #pragma unroll
    for (int mt = 0; mt < 2; ++mt) {
        int node = m0 + mt * 16 + mrow;
        if (node >= n) continue;
        #pragma unroll
        for (int ct = 0; ct < 6; ++ct) {
            int gcol0 = colbase + ct * 16 + kgrp * 4;   // 4 consecutive cols
            float4 b4 = *(const float4*)(bias + gcol0);
            float v0 = acc[mt][ct][0] + b4.x;
            float v1 = acc[mt][ct][1] + b4.y;
            float v2 = acc[mt][ct][2] + b4.z;
            float v3 = acc[mt][ct][3] + b4.w;
            __half2 h01 = __floats2half2_rn(v0, v1);
            __half2 h23 = __floats2half2_rn(v2, v3);
            uint2 pk;
            pk.x = *(unsigned int*)&h01;
            pk.y = *(unsigned int*)&h23;
            if (gcol0 < 128)
                *(uint2*)(a_half + (size_t)node * 128 + gcol0) = pk;
            else
                *(uint2*)(bh + (size_t)node * 256 + (gcol0 - 128)) = pk;
        }
    }
}

// -------- per-edge attention + row-count (symmetric); 4 units / 16-lane group --
__global__ void edge_attn_sym_kernel(const int* __restrict__ row, const int* __restrict__ col,
                                     const __half* __restrict__ a_half, float* __restrict__ attn,
                                     int* __restrict__ cnt, int E0, int nu)
{
    int gtid = blockIdx.x * blockDim.x + threadIdx.x;
    int g = gtid >> 4;
    int lane = gtid & 15;
    int ubase = 4 * g;
    if (ubase >= nu) return;
    int r[4], c[4], e[4];
    float4 av[4], bv[4];
    #pragma unroll
    for (int t = 0; t < 4; ++t) {
        int u = ubase + t;
        int uc = (u < nu) ? u : ubase;
        e[t] = (uc < E0) ? uc : uc + E0;
        r[t] = row[e[t]];
        c[t] = col[e[t]];
        av[t] = ((const float4*)(a_half + (size_t)r[t] * 128))[lane];
        bv[t] = ((const float4*)(a_half + (size_t)c[t] * 128))[lane];
    }
    float p[4];
    #pragma unroll
    for (int t = 0; t < 4; ++t) {
        const __half2* a2 = (const __half2*)&av[t];
        const __half2* b2 = (const __half2*)&bv[t];
        float s = 0.f;
        #pragma unroll
        for (int q = 0; q < 4; ++q) {
            float2 fa = __half22float2(a2[q]);
            float2 fb = __half22float2(b2[q]);
            s += fa.x * fb.x + fa.y * fb.y;
        }
        s += __shfl_xor(s, 1);
        s += __shfl_xor(s, 2);
        p[t] = s;
    }
    int h = lane >> 2, j = lane & 3;
    if (j == 0) {
        #pragma unroll
        for (int t = 0; t < 4; ++t) {
            int u = ubase + t;
            if (u >= nu) break;
            float sg = 1.0f / (1.0f + __expf(-p[t]));
            attn[(size_t)e[t]*4 + h] = sg;
            if (u < E0) attn[(size_t)(e[t] + E0)*4 + h] = sg;
        }
    }
    if (lane == 0) {
        #pragma unroll
        for (int t = 0; t < 4; ++t) {
            int u = ubase + t;
            if (u < nu && u < E0) { atomicAdd(&cnt[r[t]], 1); atomicAdd(&cnt[c[t]], 1); }
        }
    }
}

// ---------------- CSR build: 3-phase multi-block scan ----------------
__global__ __launch_bounds__(1024) void scanA_kernel(const int* __restrict__ cnt,
                                                     int* __restrict__ local,
                                                     int* __restrict__ bsum, int n)
{
    __shared__ int s[1024];
    int t = threadIdx.x;
    int i = blockIdx.x * 1024 + t;
    int v = (i < n) ? cnt[i] : 0;
    s[t] = v;
    __syncthreads();
    for (int off = 1; off < 1024; off <<= 1) {
        int tmp = (t >= off) ? s[t - off] : 0;
        __syncthreads();
        s[t] += tmp;
        __syncthreads();
    }
    if (i < n) local[i] = s[t] - v;
    if (t == 1023) bsum[blockIdx.x] = s[t];
}

__global__ __launch_bounds__(1024) void scanB_kernel(int* __restrict__ bsum,
                                                     int* __restrict__ rowp,
                                                     int nb, int n)
{
    __shared__ int s[1024];
    int t = threadIdx.x;
    int v = (t < nb) ? bsum[t] : 0;
    s[t] = v;
    __syncthreads();
    for (int off = 1; off < 1024; off <<= 1) {
        int tmp = (t >= off) ? s[t - off] : 0;
        __syncthreads();
        s[t] += tmp;
        __syncthreads();
    }
    if (t < nb) bsum[t] = s[t] - v;
    if (t == nb - 1) rowp[n] = s[t];
}

__global__ void scanC_kernel(int* __restrict__ local_nxt, const int* __restrict__ bsum,
                             int* __restrict__ rowp, int n)
{
    int i = blockIdx.x * blockDim.x + threadIdx.x;
    if (i >= n) return;
    int v = local_nxt[i] + bsum[i >> 10];
    rowp[i] = v;
    local_nxt[i] = v;
}

__global__ void scatter_kernel(const int* __restrict__ row, const int* __restrict__ col,
                               int* __restrict__ next, int* __restrict__ col_s,
                               int* __restrict__ perm, int ne2)
{
    int e = blockIdx.x * blockDim.x + threadIdx.x;
    if (e >= ne2) return;
    int pos = atomicAdd(&next[row[e]], 1);
    col_s[pos] = col[e];
    perm[pos] = e;
}

// -------- deg via CSR (no atomics), fused isq + dw: wave per row --------
__global__ __launch_bounds__(256) void deg_csr_kernel(
    const int* __restrict__ perm, const float* __restrict__ attn,
    const int* __restrict__ rowp, const float* __restrict__ coeff,
    float* __restrict__ isq, float* __restrict__ dw, int E0, int n)
{
    int wid = threadIdx.x >> 6;
    int lane = threadIdx.x & 63;
    int i = blockIdx.x * 4 + wid;
    if (i >= n) return;
    int start = rowp[i], end = rowp[i + 1];
    int h = lane & 3;
    float s = 0.f;
    for (int p = start + (lane >> 2); p < end; p += 16) {
        int e = perm[p];
        s += attn[(size_t)e * 4 + h];
    }
    s += __shfl_xor(s, 4);
    s += __shfl_xor(s, 8);
    s += __shfl_xor(s, 16);
    s += __shfl_xor(s, 32);
    if (lane < 4) {
        float al = attn[(size_t)(2 * E0 + i) * 4 + h];   // self-loop
        s += al;
        float q = (s > 0.f) ? rsqrtf(s) : 0.f;
        isq[(size_t)i * 4 + h] = q;
        dw[(size_t)i * 4 + h] = coeff[h] * al * q * q;
    }
}

// coeff layout: [0..3]=s_h ; [4 + k*4 + h]=c1 ; [4 + NIT*4 + k*4 + h]=c2
__global__ void coeff_kernel(const float* __restrict__ eps_inv, float* __restrict__ coeff)
{
    int h = threadIdx.x;
    if (h >= 4) return;
    float eps = 1.0f / (1.0f + expf(-eps_inv[h]));
    float s = 1.0f - eps;          // delta (theta = 1)
    coeff[h] = s;
    float sigma2 = 2.0f / s;       // 2*sigma1
    float rho = s;                 // rho0 = delta/theta
    for (int k = 0; k < NIT; ++k) {
        float rhon = 1.0f / (sigma2 - rho);
        coeff[4 + k*4 + h] = rhon * rho;
        coeff[4 + NIT*4 + k*4 + h] = 2.0f * rhon / s;
        rho = rhon;
    }
}

__global__ void vals_kernel(const int* __restrict__ perm, const int* __restrict__ row,
                            const int* __restrict__ col, const float* __restrict__ attn,
                            const float* __restrict__ isq, const float* __restrict__ coeff,
                            __half* __restrict__ valsh, int ne2)
{
    int p = blockIdx.x * blockDim.x + threadIdx.x;
    if (p >= ne2) return;
    int e = perm[p];
    int r0 = row[e], c0 = col[e];
    #pragma unroll
    for (int h = 0; h < 4; ++h)
        valsh[(size_t)p*4 + h] = __float2half(
            coeff[h] * attn[(size_t)e*4 + h]
            * isq[(size_t)r0*4 + h] * isq[(size_t)c0*4 + h]);
}

// ------------- gather: 8-batch main loop + exec-masked 8-batch tail -------------
__device__ __forceinline__ void gather_row(
    const __half2* __restrict__ x2, const __half* __restrict__ valsh,
    const int* __restrict__ col_s, int start, int end, int lane, int h,
    float& a0, float& a1, float& a2, float& a3)
{
    int p = start;
    for (; p + 8 <= end; p += 8) {
        float w[8];
        uint2 u[8];
        #pragma unroll
        for (int q = 0; q < 8; ++q) {
            int c = col_s[p + q];
            w[q] = __half2float(valsh[(size_t)(p + q) * 4 + h]);
            u[q] = *(const uint2*)(x2 + (size_t)c * 128 + lane * 2);
        }
        #pragma unroll
        for (int q = 0; q < 8; ++q) {
            float2 f0 = __half22float2(*(__half2*)&u[q].x);
            float2 f1 = __half22float2(*(__half2*)&u[q].y);
            a0 += w[q] * f0.x; a1 += w[q] * f0.y;
            a2 += w[q] * f1.x; a3 += w[q] * f1.y;
        }
    }
    int len = end - p;   // 0..7
    {
        float w[8];
        uint2 u[8];
        #pragma unroll
        for (int q = 0; q < 8; ++q) {
            if (q < len) {
                int c = col_s[p + q];
                w[q] = __half2float(valsh[(size_t)(p + q) * 4 + h]);
                u[q] = *(const uint2*)(x2 + (size_t)c * 128 + lane * 2);
            }
        }
        #pragma unroll
        for (int q = 0; q < 8; ++q) {
            if (q < len) {
                float2 f0 = __half22float2(*(__half2*)&u[q].x);
                float2 f1 = __half22float2(*(__half2*)&u[q].y);
                a0 += w[q] * f0.x; a1 += w[q] * f0.y;
                a2 += w[q] * f1.x; a3 += w[q] * f1.y;
            }
        }
    }
}

// ---------------- fused chebyshev iteration (ONE wave per block) ----------------
template <bool FINAL>
__global__ __launch_bounds__(64) void cheb_kernel(
    const __half* __restrict__ xch, const __half* __restrict__ xph,
    const __half* __restrict__ bh, const float* __restrict__ dw,
    __half* __restrict__ xnh, float* __restrict__ out,
    const __half* __restrict__ valsh, const int* __restrict__ col_s,
    const int* __restrict__ row_ptr, const float* __restrict__ coeff, int k, int n)
{
    int lane = threadIdx.x;
    int i = blockIdx.x;
    if (i >= n) return;
    int h = lane >> 4;
    const __half2* x2 = (const __half2*)xch;
    size_t idx2 = (size_t)i * 128 + lane * 2;
    float2 xc0 = __half22float2(x2[idx2]);
    float2 xc1 = __half22float2(x2[idx2 + 1]);
    float2 xp0 = xph ? __half22float2(((const __half2*)xph)[idx2])     : make_float2(0.f, 0.f);
    float2 xp1 = xph ? __half22float2(((const __half2*)xph)[idx2 + 1]) : make_float2(0.f, 0.f);
    float2 bv0 = __half22float2(((const __half2*)bh)[idx2]);
    float2 bv1 = __half22float2(((const __half2*)bh)[idx2 + 1]);
    float dwv = dw[(size_t)i * 4 + h];
    int start = row_ptr[i], end = row_ptr[i + 1];
    float a0 = 0.f, a1 = 0.f, a2 = 0.f, a3 = 0.f;
    gather_row(x2, valsh, col_s, start, end, lane, h, a0, a1, a2, a3);
    float r0 = bv0.x - xc0.x + a0 + dwv * xc0.x;
    float r1 = bv0.y - xc0.y + a1 + dwv * xc0.y;
    float r2 = bv1.x - xc1.x + a2 + dwv * xc1.x;
    float r3 = bv1.y - xc1.y + a3 + dwv * xc1.y;
    float c1v = coeff[4 + k*4 + h];
    float c2v = coeff[4 + NIT*4 + k*4 + h];
    float v0 = xc0.x + c1v * (xc0.x - xp0.x) + c2v * r0;
    float v1 = xc0.y + c1v * (xc0.y - xp0.y) + c2v * r1;
    float v2 = xc1.x + c1v * (xc1.x - xp1.x) + c2v * r2;
    float v3 = xc1.y + c1v * (xc1.y - xp1.y) + c2v * r3;
    if (FINAL) {
        v0 += __shfl_xor(v0, 16); v0 += __shfl_xor(v0, 32);
        v1 += __shfl_xor(v1, 16); v1 += __shfl_xor(v1, 32);
        v2 += __shfl_xor(v2, 16); v2 += __shfl_xor(v2, 32);
        v3 += __shfl_xor(v3, 16); v3 += __shfl_xor(v3, 32);
        if (lane < 16) {
            float4 o = make_float4(0.25f*v0, 0.25f*v1, 0.25f*v2, 0.25f*v3);
            ((float4*)out)[(size_t)i * 16 + lane] = o;
        }
    } else {
        __half2* xo = (__half2*)xnh;
        xo[idx2]     = __floats2half2_rn(v0, v1);
        xo[idx2 + 1] = __floats2half2_rn(v2, v3);
    }
}

__global__ void fill_kernel(float* __restrict__ out, int sz, float v)
{
    int i = blockIdx.x * blockDim.x + threadIdx.x;
    if (i < sz) out[i] = v;
}

extern "C" void kernel_launch(void* const* d_in, const int* in_sizes, int n_in,
                              void* d_out, int out_size, void* d_ws, size_t ws_size,
                              hipStream_t stream)
{
    const int*   row     = (const int*)d_in[0];
    const int*   col     = (const int*)d_in[1];
    const float* feat    = (const float*)d_in[2];
    const float* w_attn  = (const float*)d_in[3];
    const float* b_attn  = (const float*)d_in[4];
    const float* w_out   = (const float*)d_in[5];
    const float* b_out   = (const float*)d_in[6];
    const float* eps_inv = (const float*)d_in[7];
    float* out = (float*)d_out;

    int n  = in_sizes[2] / 128;
    int ne = in_sizes[0];
    int E0 = (ne - n) / 2;          // setup: edges = [r,c],[c,r],loops
    int ne2 = 2 * E0;               // CSR edges (loops excluded)
    int nb = (n + 1023) / 1024;     // scan blocks

    // workspace layout
    char* wsb = (char*)d_ws;
    size_t off = 0;
    auto alloc = [&](size_t bytes) -> void* {
        void* p = wsb + off;
        off += (bytes + 255) & ~(size_t)255;
        return p;
    };
    __half* a_half = (__half*)alloc((size_t)n * 128 * 2);
    __half* bh     = (__half*)alloc((size_t)n * 256 * 2);
    __half* hA     = (__half*)alloc((size_t)n * 256 * 2);
    __half* hB     = (__half*)alloc((size_t)n * 256 * 2);
    __half* wt     = (__half*)alloc((size_t)384 * 128 * 2);
    float*  bias   = (float*)alloc((size_t)384 * 4);
    __half* valsh  = (__half*)alloc((size_t)ne2 * 4 * 2);
    float*  isq    = (float*)alloc((size_t)n * 4 * 4);
    float*  dw     = (float*)alloc((size_t)n * 4 * 4);
    int*    rowp   = (int*)alloc((size_t)(n + 1) * 4);
    int*    col_s  = (int*)alloc((size_t)ne2 * 4);
    int*    bsum   = (int*)alloc((size_t)((nb + 63) & ~63) * 4);
    float*  coeff  = (float*)alloc((size_t)(4 + 8 * NIT) * 4);

    // overlays: consumed before the solve loop writes hA/hB
    int*   perm = (int*)hA;                                   // ne2*4 <= n*512
    int*   cnt  = (int*)((char*)hA + (((size_t)ne2*4 + 255) & ~(size_t)255));
    int*   nxt  = cnt + ((n + 64) & ~63);
    float* attn = (float*)hB;                                 // ne*4*4 <= n*512

    if (off > ws_size) {  // sentinel: distinctive absmax tells us ws is too small
        fill_kernel<<<(out_size + 255) / 256, 256, 0, stream>>>(out, out_size, 1e9f);
        return;
    }

    hipMemsetAsync(cnt, 0, (size_t)n * 4, stream);

    conv_w_kernel<<<(384 * 128 + 255) / 256, 256, 0, stream>>>(w_attn, b_attn,
                                                               w_out, b_out, wt, bias);
    mfma_gemm_kernel<<<(n + 31) / 32, 256, 0, stream>>>(feat, wt, bias, a_half, bh, n);
    coeff_kernel<<<1, 64, 0, stream>>>(eps_inv, coeff);

    int nu = E0 + n;  // edge-units: one per symmetric pair + one per loop
    int ngroups = (nu + 3) / 4;
    int ublocks = (ngroups * 16 + 255) / 256;
    edge_attn_sym_kernel<<<ublocks, 256, 0, stream>>>(row, col, a_half, attn,
                                                      cnt, E0, nu);

    scanA_kernel<<<nb, 1024, 0, stream>>>(cnt, nxt, bsum, n);
    scanB_kernel<<<1, 1024, 0, stream>>>(bsum, rowp, nb, n);
    scanC_kernel<<<(n + 255) / 256, 256, 0, stream>>>(nxt, bsum, rowp, n);
    scatter_kernel<<<(ne2 + 255) / 256, 256, 0, stream>>>(row, col, nxt, col_s, perm, ne2);
    deg_csr_kernel<<<(n + 3) / 4, 256, 0, stream>>>(perm, attn, rowp, coeff,
                                                    isq, dw, E0, n);
    vals_kernel<<<(ne2 + 255) / 256, 256, 0, stream>>>(perm, row, col, attn, isq,
                                                       coeff, valsh, ne2);

    // x0 = bh, x1 -> hA, x2 -> hB, then ping-pong (x_{k+1} overwrites x_{k-1})
    cheb_kernel<false><<<n, 64, 0, stream>>>(
        bh, nullptr, bh, dw, hA, nullptr, valsh, col_s, rowp, coeff, 0, n);
    cheb_kernel<false><<<n, 64, 0, stream>>>(
        hA, bh, bh, dw, hB, nullptr, valsh, col_s, rowp, coeff, 1, n);
    for (int k = 2; k < NIT; ++k) {
        __half* cur = (k & 1) ? hA : hB;
        __half* prv = (k & 1) ? hB : hA;
        if (k == NIT - 1)
            cheb_kernel<true><<<n, 64, 0, stream>>>(
                cur, prv, bh, dw, nullptr, out, valsh, col_s, rowp, coeff, k, n);
        else
            cheb_kernel<false><<<n, 64, 0, stream>>>(
                cur, prv, bh, dw, prv, nullptr, valsh, col_s, rowp, coeff, k, n);
    }
}